// Round 7
// baseline (1283.753 us; speedup 1.0000x reference)
//
#include <hip/hip_runtime.h>

#define NN 100000
#define NE 1600000
#define NTILE 782            // ceil(NN/128); tile = dst >> 7 (128 nodes/tile)
#define NSL 13               // src slices: slice = src >> 13
#define NBUCK (NTILE * NSL)  // 10166 buckets, key = tile*13 + slice
#define GRID_SC 40           // ceil(NBUCK/256)
#define SRC_MASK 0x1FFFF

__device__ __forceinline__ float rdlane(float v, int i) {
    return __uint_as_float(__builtin_amdgcn_readlane(__float_as_uint(v), (unsigned)i));
}

// ===================== build: per-(tile,slice) histogram =====================
__global__ __launch_bounds__(256) void hist_k(const int* __restrict__ ei,
                                              int* __restrict__ cnt) {
    int e = blockIdx.x * 256 + threadIdx.x;
    int src = ei[e];
    int dst = ei[NE + e];
    atomicAdd(&cnt[(dst >> 7) * NSL + (src >> 13)], 1);
}

__global__ __launch_bounds__(256) void scanA_k(const int* __restrict__ in,
                                               int* __restrict__ scanned,
                                               int* __restrict__ bsums, int n) {
    __shared__ int tmp[256];
    int i = blockIdx.x * 256 + threadIdx.x;
    int v = (i < n) ? in[i] : 0;
    tmp[threadIdx.x] = v;
    __syncthreads();
#pragma unroll
    for (int off = 1; off < 256; off <<= 1) {
        int t = (threadIdx.x >= off) ? tmp[threadIdx.x - off] : 0;
        __syncthreads();
        tmp[threadIdx.x] += t;
        __syncthreads();
    }
    if (i < n) scanned[i] = tmp[threadIdx.x];
    if (threadIdx.x == 255) bsums[blockIdx.x] = tmp[255];
}

// single-wave inclusive scan (n <= 64), in place
__global__ __launch_bounds__(64) void scanC_k(int* __restrict__ b, int n) {
    int t = threadIdx.x;
    int v = (t < n) ? b[t] : 0;
#pragma unroll
    for (int off = 1; off < 64; off <<= 1) {
        int u = __shfl_up(v, off);
        if (t >= off) v += u;
    }
    if (t < n) b[t] = v;
}

// Q[i] = exclusive bucket start; cursor = copy; Q[NBUCK] = NE
__global__ __launch_bounds__(256) void combine_k(const int* __restrict__ S0,
                                                 const int* __restrict__ B0,
                                                 const int* __restrict__ cnt,
                                                 int* __restrict__ Q,
                                                 int* __restrict__ cursor) {
    int i = blockIdx.x * 256 + threadIdx.x;
    if (i < NBUCK) {
        int c0 = i >> 8;
        int excl = S0[i] - cnt[i] + (c0 ? B0[c0 - 1] : 0);
        Q[i] = excl;
        cursor[i] = excl;
    }
    if (i == NBUCK) Q[i] = NE;
}

// scatter edges into (tile, slice)-major order; pack (dst&127)<<17 | src
__global__ __launch_bounds__(256) void fill_k(const int* __restrict__ ei,
                                              int* __restrict__ cursor,
                                              int* __restrict__ packed) {
    int e = blockIdx.x * 256 + threadIdx.x;
    int src = ei[e];
    int dst = ei[NE + e];
    int pos = atomicAdd(&cursor[(dst >> 7) * NSL + (src >> 13)], 1);
    packed[pos] = ((dst & 127) << 17) | src;
}

// ===================== layer 1: LDS-scatter gather(x,32ch) + MLP1 -> h =====================
// block owns tile of 128 dst nodes; 8 waves stride the tile's edge list.
// lanes 0-31 / 32-63 handle two edges per step (channel c = lane&31).
__global__ __launch_bounds__(512, 4) void fused1(const float* __restrict__ x,
                                                 const int* __restrict__ Q,
                                                 const int* __restrict__ packed,
                                                 const float* __restrict__ W1,
                                                 const float* __restrict__ b1,
                                                 const float* __restrict__ W2,
                                                 const float* __restrict__ b2,
                                                 float* __restrict__ h) {
    __shared__ float A[128 * 32];   // 16 KB
    for (int i = threadIdx.x; i < 128 * 32; i += 512) A[i] = 0.f;
    __syncthreads();

    int tile = blockIdx.x;
    int lane = threadIdx.x & 63;
    int w = threadIdx.x >> 6;
    int c = lane & 31;
    int p = lane >> 5;

    int e0 = Q[tile * NSL];
    int e1 = Q[tile * NSL + NSL];

    // each wave: pair-slot 2w+p, stride 16; 4-deep unroll (8 edges in flight/wave)
    int e = e0 + 2 * w + p;
    for (; e + 48 < e1; e += 64) {
        int pk0 = packed[e], pk1 = packed[e + 16];
        int pk2 = packed[e + 32], pk3 = packed[e + 48];
        float v0 = x[(size_t)(pk0 & SRC_MASK) * 32 + c];
        float v1 = x[(size_t)(pk1 & SRC_MASK) * 32 + c];
        float v2 = x[(size_t)(pk2 & SRC_MASK) * 32 + c];
        float v3 = x[(size_t)(pk3 & SRC_MASK) * 32 + c];
        atomicAdd(&A[(pk0 >> 17) * 32 + c], v0);
        atomicAdd(&A[(pk1 >> 17) * 32 + c], v1);
        atomicAdd(&A[(pk2 >> 17) * 32 + c], v2);
        atomicAdd(&A[(pk3 >> 17) * 32 + c], v3);
    }
    for (; e < e1; e += 16) {
        int pk = packed[e];
        atomicAdd(&A[(pk >> 17) * 32 + c], x[(size_t)(pk & SRC_MASK) * 32 + c]);
    }
    __syncthreads();

    // MLP: wave w handles rows w*16..w*16+15, batched (weights amortized x16)
    int rbase = w * 16;
    float aval[16], hid[16], o[16];
#pragma unroll
    for (int k = 0; k < 16; ++k) {
        int r = rbase + k;
        int node = tile * 128 + r;
        aval[k] = (node < NN) ? (A[r * 32 + c] + x[(size_t)node * 32 + c]) : 0.f;
    }
    float bb1 = b1[lane];
#pragma unroll
    for (int k = 0; k < 16; ++k) hid[k] = bb1;
    for (int i = 0; i < 32; ++i) {
        float wv = W1[i * 64 + lane];
#pragma unroll
        for (int k = 0; k < 16; ++k)
            hid[k] = fmaf(rdlane(aval[k], i), wv, hid[k]);
    }
#pragma unroll
    for (int k = 0; k < 16; ++k) hid[k] = fmaxf(hid[k], 0.f);

    float bb2 = b2[lane];
#pragma unroll
    for (int k = 0; k < 16; ++k) o[k] = bb2;
    for (int j = 0; j < 64; ++j) {
        float wv = W2[j * 64 + lane];
#pragma unroll
        for (int k = 0; k < 16; ++k)
            o[k] = fmaf(rdlane(hid[k], j), wv, o[k]);
    }
#pragma unroll
    for (int k = 0; k < 16; ++k) {
        int node = tile * 128 + rbase + k;
        if (node < NN)
            h[(size_t)node * 64 + lane] = fmaxf(o[k], 0.f);
    }
}

// ===================== layer 2: LDS-scatter gather(h,64ch) + MLP2 -> out =====================
__global__ __launch_bounds__(512, 4) void fused2(const float* __restrict__ h,
                                                 const int* __restrict__ Q,
                                                 const int* __restrict__ packed,
                                                 const float* __restrict__ W3,
                                                 const float* __restrict__ b3,
                                                 const float* __restrict__ W4,
                                                 const float* __restrict__ b4,
                                                 float* __restrict__ out) {
    __shared__ float A[128 * 64];   // 32 KB
    for (int i = threadIdx.x; i < 128 * 64; i += 512) A[i] = 0.f;
    __syncthreads();

    int tile = blockIdx.x;
    int lane = threadIdx.x & 63;
    int w = threadIdx.x >> 6;

    int e0 = Q[tile * NSL];
    int e1 = Q[tile * NSL + NSL];

    // wave handles edge slots e0+w, stride 8; 4-deep unroll
    int e = e0 + w;
    for (; e + 24 < e1; e += 32) {
        int pk0 = packed[e], pk1 = packed[e + 8];
        int pk2 = packed[e + 16], pk3 = packed[e + 24];
        float v0 = h[(size_t)(pk0 & SRC_MASK) * 64 + lane];
        float v1 = h[(size_t)(pk1 & SRC_MASK) * 64 + lane];
        float v2 = h[(size_t)(pk2 & SRC_MASK) * 64 + lane];
        float v3 = h[(size_t)(pk3 & SRC_MASK) * 64 + lane];
        atomicAdd(&A[(pk0 >> 17) * 64 + lane], v0);
        atomicAdd(&A[(pk1 >> 17) * 64 + lane], v1);
        atomicAdd(&A[(pk2 >> 17) * 64 + lane], v2);
        atomicAdd(&A[(pk3 >> 17) * 64 + lane], v3);
    }
    for (; e < e1; e += 8) {
        int pk = packed[e];
        atomicAdd(&A[(pk >> 17) * 64 + lane],
                  h[(size_t)(pk & SRC_MASK) * 64 + lane]);
    }
    __syncthreads();

    int rbase = w * 16;
    float aval[16], hid[16], o[16];
#pragma unroll
    for (int k = 0; k < 16; ++k) {
        int r = rbase + k;
        int node = tile * 128 + r;
        aval[k] = (node < NN) ? (A[r * 64 + lane] + h[(size_t)node * 64 + lane]) : 0.f;
    }
    float bb3 = b3[lane];
#pragma unroll
    for (int k = 0; k < 16; ++k) hid[k] = bb3;
    for (int i = 0; i < 64; ++i) {
        float wv = W3[i * 64 + lane];
#pragma unroll
        for (int k = 0; k < 16; ++k)
            hid[k] = fmaf(rdlane(aval[k], i), wv, hid[k]);
    }
#pragma unroll
    for (int k = 0; k < 16; ++k) hid[k] = fmaxf(hid[k], 0.f);

    float bb4 = b4[lane & 31];
#pragma unroll
    for (int k = 0; k < 16; ++k) o[k] = bb4;
    for (int j = 0; j < 64; ++j) {
        float wv = W4[j * 32 + (lane & 31)];
#pragma unroll
        for (int k = 0; k < 16; ++k)
            o[k] = fmaf(rdlane(hid[k], j), wv, o[k]);
    }
    if (lane < 32) {
#pragma unroll
        for (int k = 0; k < 16; ++k) {
            int node = tile * 128 + rbase + k;
            if (node < NN)
                out[(size_t)node * 32 + lane] = o[k];
        }
    }
}

extern "C" void kernel_launch(void* const* d_in, const int* in_sizes, int n_in,
                              void* d_out, int out_size, void* d_ws, size_t ws_size,
                              hipStream_t stream) {
    const float* x  = (const float*)d_in[0];
    const int*   ei = (const int*)d_in[1];
    const float* W1 = (const float*)d_in[2];
    const float* b1 = (const float*)d_in[3];
    const float* W2 = (const float*)d_in[4];
    const float* b2 = (const float*)d_in[5];
    const float* W3 = (const float*)d_in[6];
    const float* b3 = (const float*)d_in[7];
    const float* W4 = (const float*)d_in[8];
    const float* b4 = (const float*)d_in[9];
    float* out = (float*)d_out;

    char* ws = (char*)d_ws;
    float* h      = (float*)ws;               ws += (size_t)NN * 64 * 4;       // 25.6 MB
    int*   packed = (int*)ws;                 ws += (size_t)NE * 4;            // 6.4 MB
    int*   Q      = (int*)ws;                 ws += (size_t)(NBUCK + 1) * 4;   // 41 KB

    // build-time arrays overlay the h region (dead before fused1 writes h)
    char* ov = (char*)h;
    int* cnt    = (int*)ov;                   ov += (size_t)NBUCK * 4;
    int* S0     = (int*)ov;                   ov += (size_t)NBUCK * 4;
    int* cursor = (int*)ov;                   ov += (size_t)NBUCK * 4;
    int* B0     = (int*)ov;                   ov += (size_t)GRID_SC * 4;

    // ---- (tile,slice)-bucketed edge sort ----
    hipMemsetAsync(cnt, 0, (size_t)NBUCK * 4, stream);
    hist_k<<<NE / 256, 256, 0, stream>>>(ei, cnt);
    scanA_k<<<GRID_SC, 256, 0, stream>>>(cnt, S0, B0, NBUCK);
    scanC_k<<<1, 64, 0, stream>>>(B0, GRID_SC);
    combine_k<<<GRID_SC, 256, 0, stream>>>(S0, B0, cnt, Q, cursor);
    fill_k<<<NE / 256, 256, 0, stream>>>(ei, cursor, packed);

    // ---- fused layers: one block per 128-node dst tile ----
    fused1<<<NTILE, 512, 0, stream>>>(x, Q, packed, W1, b1, W2, b2, h);
    fused2<<<NTILE, 512, 0, stream>>>(h, Q, packed, W3, b3, W4, b4, out);
}

// Round 8
// 1083.628 us; speedup vs baseline: 1.1847x; 1.1847x over previous
//
#include <hip/hip_runtime.h>

#define NN 100000
#define NE 1600000
#define NTILE 1563           // ceil(NN/64); tile = dst >> 6 (64 nodes/tile)
#define NSL 13               // src slices: slice = src >> 13
#define NBUCK (NTILE * NSL)  // 20319 buckets, key = tile*13 + slice
#define GRID_SC 80           // ceil(NBUCK/256)
#define SRC_MASK 0x1FFFF

__device__ __forceinline__ float rdlane(float v, int i) {
    return __uint_as_float(__builtin_amdgcn_readlane(__float_as_uint(v), (unsigned)i));
}

// ===================== build: per-(tile,slice) histogram =====================
__global__ __launch_bounds__(256) void hist_k(const int* __restrict__ ei,
                                              int* __restrict__ cnt) {
    int e = blockIdx.x * 256 + threadIdx.x;
    int src = ei[e];
    int dst = ei[NE + e];
    atomicAdd(&cnt[(dst >> 6) * NSL + (src >> 13)], 1);
}

__global__ __launch_bounds__(256) void scanA_k(const int* __restrict__ in,
                                               int* __restrict__ scanned,
                                               int* __restrict__ bsums, int n) {
    __shared__ int tmp[256];
    int i = blockIdx.x * 256 + threadIdx.x;
    int v = (i < n) ? in[i] : 0;
    tmp[threadIdx.x] = v;
    __syncthreads();
#pragma unroll
    for (int off = 1; off < 256; off <<= 1) {
        int t = (threadIdx.x >= off) ? tmp[threadIdx.x - off] : 0;
        __syncthreads();
        tmp[threadIdx.x] += t;
        __syncthreads();
    }
    if (i < n) scanned[i] = tmp[threadIdx.x];
    if (threadIdx.x == 255) bsums[blockIdx.x] = tmp[255];
}

// single-block inclusive scan (n <= 256), in place
__global__ __launch_bounds__(256) void scanB_k(int* __restrict__ b, int n) {
    __shared__ int tmp[256];
    int t = threadIdx.x;
    tmp[t] = (t < n) ? b[t] : 0;
    __syncthreads();
#pragma unroll
    for (int off = 1; off < 256; off <<= 1) {
        int u = (t >= off) ? tmp[t - off] : 0;
        __syncthreads();
        tmp[t] += u;
        __syncthreads();
    }
    if (t < n) b[t] = tmp[t];
}

// Q[i] = exclusive bucket start; cursor = copy; Q[NBUCK] = NE
__global__ __launch_bounds__(256) void combine_k(const int* __restrict__ S0,
                                                 const int* __restrict__ B0,
                                                 const int* __restrict__ cnt,
                                                 int* __restrict__ Q,
                                                 int* __restrict__ cursor) {
    int i = blockIdx.x * 256 + threadIdx.x;
    if (i < NBUCK) {
        int c0 = i >> 8;
        int excl = S0[i] - cnt[i] + (c0 ? B0[c0 - 1] : 0);
        Q[i] = excl;
        cursor[i] = excl;
    }
    if (i == NBUCK) Q[i] = NE;
}

// scatter edges into (tile, slice)-major order; pack (dst&63)<<17 | src
__global__ __launch_bounds__(256) void fill_k(const int* __restrict__ ei,
                                              int* __restrict__ cursor,
                                              int* __restrict__ packed) {
    int e = blockIdx.x * 256 + threadIdx.x;
    int src = ei[e];
    int dst = ei[NE + e];
    int pos = atomicAdd(&cursor[(dst >> 6) * NSL + (src >> 13)], 1);
    packed[pos] = ((dst & 63) << 17) | src;
}

// ===================== layer 1: LDS-scatter gather(x,32ch) + MLP1 -> h =====================
// block owns 64-node dst tile; 8 waves stride the tile's contiguous edge list.
// lanes 0-31 / 32-63 handle two edges per step (channel c = lane&31).
__global__ __launch_bounds__(512, 6) void fused1(const float* __restrict__ x,
                                                 const int* __restrict__ Q,
                                                 const int* __restrict__ packed,
                                                 const float* __restrict__ W1,
                                                 const float* __restrict__ b1,
                                                 const float* __restrict__ W2,
                                                 const float* __restrict__ b2,
                                                 float* __restrict__ h) {
    __shared__ float A[64 * 32];   // 8 KB
    for (int i = threadIdx.x; i < 64 * 32; i += 512) A[i] = 0.f;
    __syncthreads();

    int tile = blockIdx.x;
    int lane = threadIdx.x & 63;
    int w = threadIdx.x >> 6;
    int c = lane & 31;
    int p = lane >> 5;

    int e0 = Q[tile * NSL];
    int e1 = Q[tile * NSL + NSL];

    // half-wave handles pair-slot 2w+p, stride 16; 4-deep unroll
    int e = e0 + 2 * w + p;
    for (; e + 48 < e1; e += 64) {
        int pk0 = packed[e], pk1 = packed[e + 16];
        int pk2 = packed[e + 32], pk3 = packed[e + 48];
        float v0 = x[(size_t)(pk0 & SRC_MASK) * 32 + c];
        float v1 = x[(size_t)(pk1 & SRC_MASK) * 32 + c];
        float v2 = x[(size_t)(pk2 & SRC_MASK) * 32 + c];
        float v3 = x[(size_t)(pk3 & SRC_MASK) * 32 + c];
        atomicAdd(&A[(pk0 >> 17) * 32 + c], v0);
        atomicAdd(&A[(pk1 >> 17) * 32 + c], v1);
        atomicAdd(&A[(pk2 >> 17) * 32 + c], v2);
        atomicAdd(&A[(pk3 >> 17) * 32 + c], v3);
    }
    for (; e < e1; e += 16) {
        int pk = packed[e];
        atomicAdd(&A[(pk >> 17) * 32 + c], x[(size_t)(pk & SRC_MASK) * 32 + c]);
    }
    __syncthreads();

    // MLP: wave w handles rows w*8..w*8+7 (8-node register batch, no spill)
    int rbase = w * 8;
    float aval[8], hid[8], o[8];
#pragma unroll
    for (int k = 0; k < 8; ++k) {
        int r = rbase + k;
        int node = tile * 64 + r;
        aval[k] = (node < NN) ? (A[r * 32 + c] + x[(size_t)node * 32 + c]) : 0.f;
    }
    float bb1 = b1[lane];
#pragma unroll
    for (int k = 0; k < 8; ++k) hid[k] = bb1;
    for (int i = 0; i < 32; ++i) {
        float wv = W1[i * 64 + lane];
#pragma unroll
        for (int k = 0; k < 8; ++k)
            hid[k] = fmaf(rdlane(aval[k], i), wv, hid[k]);
    }
#pragma unroll
    for (int k = 0; k < 8; ++k) hid[k] = fmaxf(hid[k], 0.f);

    float bb2 = b2[lane];
#pragma unroll
    for (int k = 0; k < 8; ++k) o[k] = bb2;
    for (int j = 0; j < 64; ++j) {
        float wv = W2[j * 64 + lane];
#pragma unroll
        for (int k = 0; k < 8; ++k)
            o[k] = fmaf(rdlane(hid[k], j), wv, o[k]);
    }
#pragma unroll
    for (int k = 0; k < 8; ++k) {
        int node = tile * 64 + rbase + k;
        if (node < NN)
            h[(size_t)node * 64 + lane] = fmaxf(o[k], 0.f);
    }
}

// ===================== layer 2: LDS-scatter gather(h,64ch) + MLP2 -> out =====================
__global__ __launch_bounds__(512, 6) void fused2(const float* __restrict__ h,
                                                 const int* __restrict__ Q,
                                                 const int* __restrict__ packed,
                                                 const float* __restrict__ W3,
                                                 const float* __restrict__ b3,
                                                 const float* __restrict__ W4,
                                                 const float* __restrict__ b4,
                                                 float* __restrict__ out) {
    __shared__ float A[64 * 64];   // 16 KB
    for (int i = threadIdx.x; i < 64 * 64; i += 512) A[i] = 0.f;
    __syncthreads();

    int tile = blockIdx.x;
    int lane = threadIdx.x & 63;
    int w = threadIdx.x >> 6;

    int e0 = Q[tile * NSL];
    int e1 = Q[tile * NSL + NSL];

    // wave handles edge slot e0+w, stride 8; 4-deep unroll
    int e = e0 + w;
    for (; e + 24 < e1; e += 32) {
        int pk0 = packed[e], pk1 = packed[e + 8];
        int pk2 = packed[e + 16], pk3 = packed[e + 24];
        float v0 = h[(size_t)(pk0 & SRC_MASK) * 64 + lane];
        float v1 = h[(size_t)(pk1 & SRC_MASK) * 64 + lane];
        float v2 = h[(size_t)(pk2 & SRC_MASK) * 64 + lane];
        float v3 = h[(size_t)(pk3 & SRC_MASK) * 64 + lane];
        atomicAdd(&A[(pk0 >> 17) * 64 + lane], v0);
        atomicAdd(&A[(pk1 >> 17) * 64 + lane], v1);
        atomicAdd(&A[(pk2 >> 17) * 64 + lane], v2);
        atomicAdd(&A[(pk3 >> 17) * 64 + lane], v3);
    }
    for (; e < e1; e += 8) {
        int pk = packed[e];
        atomicAdd(&A[(pk >> 17) * 64 + lane],
                  h[(size_t)(pk & SRC_MASK) * 64 + lane]);
    }
    __syncthreads();

    int rbase = w * 8;
    float aval[8], hid[8], o[8];
#pragma unroll
    for (int k = 0; k < 8; ++k) {
        int r = rbase + k;
        int node = tile * 64 + r;
        aval[k] = (node < NN) ? (A[r * 64 + lane] + h[(size_t)node * 64 + lane]) : 0.f;
    }
    float bb3 = b3[lane];
#pragma unroll
    for (int k = 0; k < 8; ++k) hid[k] = bb3;
    for (int i = 0; i < 64; ++i) {
        float wv = W3[i * 64 + lane];
#pragma unroll
        for (int k = 0; k < 8; ++k)
            hid[k] = fmaf(rdlane(aval[k], i), wv, hid[k]);
    }
#pragma unroll
    for (int k = 0; k < 8; ++k) hid[k] = fmaxf(hid[k], 0.f);

    float bb4 = b4[lane & 31];
#pragma unroll
    for (int k = 0; k < 8; ++k) o[k] = bb4;
    for (int j = 0; j < 64; ++j) {
        float wv = W4[j * 32 + (lane & 31)];
#pragma unroll
        for (int k = 0; k < 8; ++k)
            o[k] = fmaf(rdlane(hid[k], j), wv, o[k]);
    }
    if (lane < 32) {
#pragma unroll
        for (int k = 0; k < 8; ++k) {
            int node = tile * 64 + rbase + k;
            if (node < NN)
                out[(size_t)node * 32 + lane] = o[k];
        }
    }
}

extern "C" void kernel_launch(void* const* d_in, const int* in_sizes, int n_in,
                              void* d_out, int out_size, void* d_ws, size_t ws_size,
                              hipStream_t stream) {
    const float* x  = (const float*)d_in[0];
    const int*   ei = (const int*)d_in[1];
    const float* W1 = (const float*)d_in[2];
    const float* b1 = (const float*)d_in[3];
    const float* W2 = (const float*)d_in[4];
    const float* b2 = (const float*)d_in[5];
    const float* W3 = (const float*)d_in[6];
    const float* b3 = (const float*)d_in[7];
    const float* W4 = (const float*)d_in[8];
    const float* b4 = (const float*)d_in[9];
    float* out = (float*)d_out;

    char* ws = (char*)d_ws;
    float* h      = (float*)ws;               ws += (size_t)NN * 64 * 4;       // 25.6 MB
    int*   packed = (int*)ws;                 ws += (size_t)NE * 4;            // 6.4 MB
    int*   Q      = (int*)ws;                 ws += (size_t)(NBUCK + 1) * 4;   // 81 KB

    // build-time arrays overlay the h region (dead before fused1 writes h)
    char* ov = (char*)h;
    int* cnt    = (int*)ov;                   ov += (size_t)NBUCK * 4;
    int* S0     = (int*)ov;                   ov += (size_t)NBUCK * 4;
    int* cursor = (int*)ov;                   ov += (size_t)NBUCK * 4;
    int* B0     = (int*)ov;                   ov += (size_t)GRID_SC * 4;

    // ---- (tile,slice)-bucketed edge sort ----
    hipMemsetAsync(cnt, 0, (size_t)NBUCK * 4, stream);
    hist_k<<<NE / 256, 256, 0, stream>>>(ei, cnt);
    scanA_k<<<GRID_SC, 256, 0, stream>>>(cnt, S0, B0, NBUCK);
    scanB_k<<<1, 256, 0, stream>>>(B0, GRID_SC);
    combine_k<<<GRID_SC, 256, 0, stream>>>(S0, B0, cnt, Q, cursor);
    fill_k<<<NE / 256, 256, 0, stream>>>(ei, cursor, packed);

    // ---- fused layers: one block per 64-node dst tile ----
    fused1<<<NTILE, 512, 0, stream>>>(x, Q, packed, W1, b1, W2, b2, h);
    fused2<<<NTILE, 512, 0, stream>>>(h, Q, packed, W3, b3, W4, b4, out);
}

// Round 9
// 1035.638 us; speedup vs baseline: 1.2396x; 1.0463x over previous
//
#include <hip/hip_runtime.h>

#define NN 100000
#define NE 1600000
#define NTILE 3125           // NN/32 exactly; tile = dst >> 5 (32 nodes/tile)
#define NSL 13               // src slices: slice = src >> 13
#define NBUCK (NTILE * NSL)  // 40625 buckets, key = tile*13 + slice
#define GRID_SC 159          // ceil(NBUCK/256)
#define SRC_MASK 0x1FFFF

__device__ __forceinline__ float rdlane(float v, int i) {
    return __uint_as_float(__builtin_amdgcn_readlane(__float_as_uint(v), (unsigned)i));
}

// ===================== build: per-(tile,slice) histogram =====================
__global__ __launch_bounds__(256) void hist_k(const int* __restrict__ ei,
                                              int* __restrict__ cnt) {
    int e = blockIdx.x * 256 + threadIdx.x;
    int src = ei[e];
    int dst = ei[NE + e];
    atomicAdd(&cnt[(dst >> 5) * NSL + (src >> 13)], 1);
}

__global__ __launch_bounds__(256) void scanA_k(const int* __restrict__ in,
                                               int* __restrict__ scanned,
                                               int* __restrict__ bsums, int n) {
    __shared__ int tmp[256];
    int i = blockIdx.x * 256 + threadIdx.x;
    int v = (i < n) ? in[i] : 0;
    tmp[threadIdx.x] = v;
    __syncthreads();
#pragma unroll
    for (int off = 1; off < 256; off <<= 1) {
        int t = (threadIdx.x >= off) ? tmp[threadIdx.x - off] : 0;
        __syncthreads();
        tmp[threadIdx.x] += t;
        __syncthreads();
    }
    if (i < n) scanned[i] = tmp[threadIdx.x];
    if (threadIdx.x == 255) bsums[blockIdx.x] = tmp[255];
}

// single-block inclusive scan (n <= 256), in place
__global__ __launch_bounds__(256) void scanB_k(int* __restrict__ b, int n) {
    __shared__ int tmp[256];
    int t = threadIdx.x;
    tmp[t] = (t < n) ? b[t] : 0;
    __syncthreads();
#pragma unroll
    for (int off = 1; off < 256; off <<= 1) {
        int u = (t >= off) ? tmp[t - off] : 0;
        __syncthreads();
        tmp[t] += u;
        __syncthreads();
    }
    if (t < n) b[t] = tmp[t];
}

// Q[i] = exclusive bucket start; cursor = copy; Q[NBUCK] = NE
__global__ __launch_bounds__(256) void combine_k(const int* __restrict__ S0,
                                                 const int* __restrict__ B0,
                                                 const int* __restrict__ cnt,
                                                 int* __restrict__ Q,
                                                 int* __restrict__ cursor) {
    int i = blockIdx.x * 256 + threadIdx.x;
    if (i < NBUCK) {
        int c0 = i >> 8;
        int excl = S0[i] - cnt[i] + (c0 ? B0[c0 - 1] : 0);
        Q[i] = excl;
        cursor[i] = excl;
    }
    if (i == NBUCK) Q[i] = NE;
}

// scatter edges into (tile, slice)-major order; pack (dst&31)<<17 | src
__global__ __launch_bounds__(256) void fill_k(const int* __restrict__ ei,
                                              int* __restrict__ cursor,
                                              int* __restrict__ packed) {
    int e = blockIdx.x * 256 + threadIdx.x;
    int src = ei[e];
    int dst = ei[NE + e];
    int pos = atomicAdd(&cursor[(dst >> 5) * NSL + (src >> 13)], 1);
    packed[pos] = ((dst & 31) << 17) | src;
}

// ===================== layer 1: LDS-scatter gather(x,32ch) + MLP1 -> h =====================
// block (4 waves) owns 32-node dst tile; waves stride the contiguous slice-sorted
// edge list; lanes 0-31 / 32-63 handle two edges per step (channel c = lane&31).
__global__ __launch_bounds__(256) void fused1(const float* __restrict__ x,
                                              const int* __restrict__ Q,
                                              const int* __restrict__ packed,
                                              const float* __restrict__ W1,
                                              const float* __restrict__ b1,
                                              const float* __restrict__ W2,
                                              const float* __restrict__ b2,
                                              float* __restrict__ h) {
    __shared__ float A[32 * 32];   // 4 KB
    for (int i = threadIdx.x; i < 32 * 32; i += 256) A[i] = 0.f;
    __syncthreads();

    int tile = blockIdx.x;
    int lane = threadIdx.x & 63;
    int w = threadIdx.x >> 6;      // wave 0..3
    int c = lane & 31;
    int p = lane >> 5;

    int e0 = Q[tile * NSL];
    int e1 = Q[tile * NSL + NSL];

    // half-wave slot 2w+p (0..7), stride 8; 4-deep unroll
    int e = e0 + 2 * w + p;
    for (; e + 24 < e1; e += 32) {
        int pk0 = packed[e], pk1 = packed[e + 8];
        int pk2 = packed[e + 16], pk3 = packed[e + 24];
        float v0 = x[(size_t)(pk0 & SRC_MASK) * 32 + c];
        float v1 = x[(size_t)(pk1 & SRC_MASK) * 32 + c];
        float v2 = x[(size_t)(pk2 & SRC_MASK) * 32 + c];
        float v3 = x[(size_t)(pk3 & SRC_MASK) * 32 + c];
        atomicAdd(&A[(pk0 >> 17) * 32 + c], v0);
        atomicAdd(&A[(pk1 >> 17) * 32 + c], v1);
        atomicAdd(&A[(pk2 >> 17) * 32 + c], v2);
        atomicAdd(&A[(pk3 >> 17) * 32 + c], v3);
    }
    for (; e < e1; e += 8) {
        int pk = packed[e];
        atomicAdd(&A[(pk >> 17) * 32 + c], x[(size_t)(pk & SRC_MASK) * 32 + c]);
    }
    __syncthreads();

    // MLP: wave w handles rows w*8..w*8+7 (8-node register batch)
    int rbase = w * 8;
    int nodeb = tile * 32 + rbase;
    float aval[8], hid[8], o[8];
#pragma unroll
    for (int k = 0; k < 8; ++k)
        aval[k] = A[(rbase + k) * 32 + c] + x[(size_t)(nodeb + k) * 32 + c];

    float bb1 = b1[lane];
#pragma unroll
    for (int k = 0; k < 8; ++k) hid[k] = bb1;
    for (int i = 0; i < 32; ++i) {
        float wv = W1[i * 64 + lane];
#pragma unroll
        for (int k = 0; k < 8; ++k)
            hid[k] = fmaf(rdlane(aval[k], i), wv, hid[k]);
    }
#pragma unroll
    for (int k = 0; k < 8; ++k) hid[k] = fmaxf(hid[k], 0.f);

    float bb2 = b2[lane];
#pragma unroll
    for (int k = 0; k < 8; ++k) o[k] = bb2;
    for (int j = 0; j < 64; ++j) {
        float wv = W2[j * 64 + lane];
#pragma unroll
        for (int k = 0; k < 8; ++k)
            o[k] = fmaf(rdlane(hid[k], j), wv, o[k]);
    }
#pragma unroll
    for (int k = 0; k < 8; ++k)
        h[(size_t)(nodeb + k) * 64 + lane] = fmaxf(o[k], 0.f);
}

// ===================== layer 2: LDS-scatter gather(h,64ch) + MLP2 -> out =====================
__global__ __launch_bounds__(256) void fused2(const float* __restrict__ h,
                                              const int* __restrict__ Q,
                                              const int* __restrict__ packed,
                                              const float* __restrict__ W3,
                                              const float* __restrict__ b3,
                                              const float* __restrict__ W4,
                                              const float* __restrict__ b4,
                                              float* __restrict__ out) {
    __shared__ float A[32 * 64];   // 8 KB
    for (int i = threadIdx.x; i < 32 * 64; i += 256) A[i] = 0.f;
    __syncthreads();

    int tile = blockIdx.x;
    int lane = threadIdx.x & 63;
    int w = threadIdx.x >> 6;

    int e0 = Q[tile * NSL];
    int e1 = Q[tile * NSL + NSL];

    // wave slot w (0..3), stride 4; 4-deep unroll
    int e = e0 + w;
    for (; e + 12 < e1; e += 16) {
        int pk0 = packed[e], pk1 = packed[e + 4];
        int pk2 = packed[e + 8], pk3 = packed[e + 12];
        float v0 = h[(size_t)(pk0 & SRC_MASK) * 64 + lane];
        float v1 = h[(size_t)(pk1 & SRC_MASK) * 64 + lane];
        float v2 = h[(size_t)(pk2 & SRC_MASK) * 64 + lane];
        float v3 = h[(size_t)(pk3 & SRC_MASK) * 64 + lane];
        atomicAdd(&A[(pk0 >> 17) * 64 + lane], v0);
        atomicAdd(&A[(pk1 >> 17) * 64 + lane], v1);
        atomicAdd(&A[(pk2 >> 17) * 64 + lane], v2);
        atomicAdd(&A[(pk3 >> 17) * 64 + lane], v3);
    }
    for (; e < e1; e += 4) {
        int pk = packed[e];
        atomicAdd(&A[(pk >> 17) * 64 + lane],
                  h[(size_t)(pk & SRC_MASK) * 64 + lane]);
    }
    __syncthreads();

    int rbase = w * 8;
    int nodeb = tile * 32 + rbase;
    float aval[8], hid[8], o[8];
#pragma unroll
    for (int k = 0; k < 8; ++k)
        aval[k] = A[(rbase + k) * 64 + lane] + h[(size_t)(nodeb + k) * 64 + lane];

    float bb3 = b3[lane];
#pragma unroll
    for (int k = 0; k < 8; ++k) hid[k] = bb3;
    for (int i = 0; i < 64; ++i) {
        float wv = W3[i * 64 + lane];
#pragma unroll
        for (int k = 0; k < 8; ++k)
            hid[k] = fmaf(rdlane(aval[k], i), wv, hid[k]);
    }
#pragma unroll
    for (int k = 0; k < 8; ++k) hid[k] = fmaxf(hid[k], 0.f);

    float bb4 = b4[lane & 31];
#pragma unroll
    for (int k = 0; k < 8; ++k) o[k] = bb4;
    for (int j = 0; j < 64; ++j) {
        float wv = W4[j * 32 + (lane & 31)];
#pragma unroll
        for (int k = 0; k < 8; ++k)
            o[k] = fmaf(rdlane(hid[k], j), wv, o[k]);
    }
    if (lane < 32) {
#pragma unroll
        for (int k = 0; k < 8; ++k)
            out[(size_t)(nodeb + k) * 32 + lane] = o[k];
    }
}

extern "C" void kernel_launch(void* const* d_in, const int* in_sizes, int n_in,
                              void* d_out, int out_size, void* d_ws, size_t ws_size,
                              hipStream_t stream) {
    const float* x  = (const float*)d_in[0];
    const int*   ei = (const int*)d_in[1];
    const float* W1 = (const float*)d_in[2];
    const float* b1 = (const float*)d_in[3];
    const float* W2 = (const float*)d_in[4];
    const float* b2 = (const float*)d_in[5];
    const float* W3 = (const float*)d_in[6];
    const float* b3 = (const float*)d_in[7];
    const float* W4 = (const float*)d_in[8];
    const float* b4 = (const float*)d_in[9];
    float* out = (float*)d_out;

    char* ws = (char*)d_ws;
    float* h      = (float*)ws;               ws += (size_t)NN * 64 * 4;       // 25.6 MB
    int*   packed = (int*)ws;                 ws += (size_t)NE * 4;            // 6.4 MB
    int*   Q      = (int*)ws;                 ws += (size_t)(NBUCK + 1) * 4;   // 163 KB

    // build-time arrays overlay the h region (dead before fused1 writes h)
    char* ov = (char*)h;
    int* cnt    = (int*)ov;                   ov += (size_t)NBUCK * 4;
    int* S0     = (int*)ov;                   ov += (size_t)NBUCK * 4;
    int* cursor = (int*)ov;                   ov += (size_t)NBUCK * 4;
    int* B0     = (int*)ov;                   ov += (size_t)GRID_SC * 4;

    // ---- (tile,slice)-bucketed edge sort ----
    hipMemsetAsync(cnt, 0, (size_t)NBUCK * 4, stream);
    hist_k<<<NE / 256, 256, 0, stream>>>(ei, cnt);
    scanA_k<<<GRID_SC, 256, 0, stream>>>(cnt, S0, B0, NBUCK);
    scanB_k<<<1, 256, 0, stream>>>(B0, GRID_SC);
    combine_k<<<GRID_SC, 256, 0, stream>>>(S0, B0, cnt, Q, cursor);
    fill_k<<<NE / 256, 256, 0, stream>>>(ei, cursor, packed);

    // ---- fused layers: one 256-thread block per 32-node dst tile ----
    fused1<<<NTILE, 256, 0, stream>>>(x, Q, packed, W1, b1, W2, b2, h);
    fused2<<<NTILE, 256, 0, stream>>>(h, Q, packed, W3, b3, W4, b4, out);
}